// Round 6
// baseline (247.710 us; speedup 1.0000x reference)
//
#include <hip/hip_runtime.h>
#include <math.h>

#define VV 32000
#define TT 128
#define EE 64
#define NN 1024
#define NPART 500   // one softmax partial per (topic, v-tile-block)

static constexpr float BOUND    = 1.41421356237309515f;   // sqrt(2)
static constexpr float LOG_SMIN = -2.30258509299404568f;  // log(0.1)
static constexpr float LOG_SMAX =  2.30258509299404568f;  // log(10)
static constexpr float LN2      =  0.69314718055994531f;
static constexpr float LOG2E    =  1.44269504088896340f;
static constexpr float E_LOG2PI =  64.0f * 1.83787706640934548f; // E*log(2*pi)

typedef __attribute__((ext_vector_type(2)))  float f32x2;    // -> v_pk_*_f32
typedef __attribute__((ext_vector_type(8)))  short short8;   // 8 bf16 = 4 VGPRs
typedef __attribute__((ext_vector_type(16))) float float16;  // MFMA 32x32 acc

static __device__ inline unsigned short f2bf(float f) {
    union { float f; unsigned u; } v; v.f = f;
    unsigned r = v.u + 0x7FFFu + ((v.u >> 16) & 1u);  // round-to-nearest-even
    return (unsigned short)(r >> 16);
}

// one instruction packs two f32 -> two bf16 (RNE, identical to f2bf)
static __device__ inline unsigned pack_bf16(float a, float b) {
    unsigned r;
    asm("v_cvt_pk_bf16_f32 %0, %1, %2" : "=v"(r) : "v"(a), "v"(b));
    return r;
}

// ---------------- kernel 0: ctx clamp+exp (blocks 0..31) + x transpose (blocks 32..63) ----------------
__global__ __launch_bounds__(256) void prep_xpose(const float* __restrict__ mu_c,
                                                  const float* __restrict__ log_sigma_c,
                                                  const float* __restrict__ x,
                                                  float* __restrict__ sc,
                                                  float* __restrict__ mc,
                                                  unsigned short* __restrict__ xT) {
    const int tid = threadIdx.x;
    if (blockIdx.x < 32) {
        int i = blockIdx.x * 256 + tid;
        if (i < TT * EE) {
            float ls = log_sigma_c[i];
            ls = fminf(fmaxf(ls, LOG_SMIN), LOG_SMAX);
            sc[i] = __expf(ls);
            float m = mu_c[i];
            mc[i] = fminf(fmaxf(m, -BOUND), BOUND);
        }
    } else {
        // transpose x [T][N] -> xT [N][T] bf16. 32 blocks x 32 n-cols.
        const int b = blockIdx.x - 32;         // 0..31
        const int n = b * 32 + (tid & 31);
        const int th = tid >> 5;               // 0..7
        const float* __restrict__ xp = x + n;
#pragma unroll
        for (int i = 0; i < 16; i += 2) {
            int t = th * 16 + i;
            float x0 = xp[(size_t)t * NN];     // lanes -> consecutive n: coalesced
            float x1 = xp[(size_t)(t + 1) * NN];
            *(unsigned*)&xT[n * TT + t] = (unsigned)f2bf(x0) | ((unsigned)f2bf(x1) << 16);
        }
    }
}

// ---------------- kernel 1: logits [V][T] (row-major), E split across waves ----------------
__global__ __launch_bounds__(256) void logits_kernel(const float* __restrict__ mu,
                                                     const float* __restrict__ log_sigma,
                                                     const float* __restrict__ sc,
                                                     const float* __restrict__ mc,
                                                     float* __restrict__ logitsVT,
                                                     float* __restrict__ pm,
                                                     float* __restrict__ pl) {
    __shared__ float part[16][4][64];  // [t-in-phase][wave][lane] : 16 KB
    __shared__ float lvt[64][33];      // [v][t-in-block], +1 pad: col-write conflict-free
    const int tid  = threadIdx.x;
    const int lane = tid & 63;
    const int wv   = tid >> 6;
    const int v0   = blockIdx.x * 64;
    const int t0   = blockIdx.y * 32;
    const int e0u  = __builtin_amdgcn_readfirstlane(wv) * 16;  // provably uniform

    // per-lane slice of sigma_v / mu_v: v = v0+lane, e in [e0u, e0u+16)
    f32x2 sv[8], mv[8];
    {
        const float* __restrict__ lsp = log_sigma + (size_t)(v0 + lane) * EE + e0u;
        const float* __restrict__ mup = mu        + (size_t)(v0 + lane) * EE + e0u;
#pragma unroll
        for (int j = 0; j < 8; j++) {
            float a = lsp[2 * j], b = lsp[2 * j + 1];
            a = fminf(fmaxf(a, LOG_SMIN), LOG_SMAX);
            b = fminf(fmaxf(b, LOG_SMIN), LOG_SMAX);
            sv[j] = f32x2{__expf(a), __expf(b)};
            float c = mup[2 * j], d = mup[2 * j + 1];
            mv[j] = f32x2{fminf(fmaxf(c, -BOUND), BOUND), fminf(fmaxf(d, -BOUND), BOUND)};
        }
    }

    // double-buffered wave-uniform ctx slices (16 sc + 16 mc floats per topic)
    f32x2 cs[2][8], cm[2][8];
    {
        const f32x2* __restrict__ sp = (const f32x2*)(sc + t0 * EE + e0u);
        const f32x2* __restrict__ mp = (const f32x2*)(mc + t0 * EE + e0u);
#pragma unroll
        for (int j = 0; j < 8; j++) { cs[0][j] = sp[j]; cm[0][j] = mp[j]; }
    }

    for (int tb = 0; tb < 2; tb++) {           // 2 phases x 16 topics = 32 topics
#pragma unroll
        for (int i = 0; i < 16; i++) {
            const int ti  = tb * 16 + i;       // 0..31 within block
            const int cur = ti & 1;
            if (ti < 31) {                     // prefetch next topic's slice
                const int tn = t0 + ti + 1;
                const f32x2* __restrict__ sp = (const f32x2*)(sc + tn * EE + e0u);
                const f32x2* __restrict__ mp = (const f32x2*)(mc + tn * EE + e0u);
#pragma unroll
                for (int j = 0; j < 8; j++) { cs[cur ^ 1][j] = sp[j]; cm[cur ^ 1][j] = mp[j]; }
            }
            f32x2 q = {0.f, 0.f};
            f32x2 p = {1.f, 1.f};
#pragma unroll
            for (int j = 0; j < 8; j++) {
                f32x2 s = sv[j] + cs[cur][j];   // v_pk_add_f32
                p *= s;                          // v_pk_mul_f32
                f32x2 d = mv[j] - cm[cur][j];
                f32x2 r;
                r.x = __builtin_amdgcn_rcpf(s.x);
                r.y = __builtin_amdgcn_rcpf(s.y);
                q += d * d * r;
            }
            // 16 factors, s in [0.2,20]: product in [6.6e-12, 6.6e20] — fp32 safe
            part[i][wv][lane] = __log2f(p.x * p.y) * LN2 + q.x + q.y;
        }
        __syncthreads();
        // finalize: wave wv owns topics i = 4*wv..4*wv+3 of this phase
#pragma unroll
        for (int k = 0; k < 4; k++) {
            const int i = wv * 4 + k;
            const int t = t0 + tb * 16 + i;
            float sum = part[i][0][lane] + part[i][1][lane] + part[i][2][lane] + part[i][3][lane];
            float logit = -0.5f * (sum + E_LOG2PI);
            lvt[lane][tb * 16 + i] = logit;    // stride-33 column write: conflict-free

            float m = logit;
#pragma unroll
            for (int off = 1; off < 64; off <<= 1) m = fmaxf(m, __shfl_xor(m, off));
            float sx = __expf(logit - m);
#pragma unroll
            for (int off = 1; off < 64; off <<= 1) sx += __shfl_xor(sx, off);
            if (lane == 0) {
                pm[t * NPART + blockIdx.x] = m;
                pl[t * NPART + blockIdx.x] = sx;
            }
        }
        __syncthreads();  // part[] reused next phase; also covers lvt before writeout
    }

    // write-out: [V][T] rows, 8 floats (32 B) per thread, 128 B per 4-thread group
    {
        const int v  = tid >> 2;
        const int c0 = (tid & 3) * 8;
        float4 d0, d1;
        d0.x = lvt[v][c0 + 0]; d0.y = lvt[v][c0 + 1];
        d0.z = lvt[v][c0 + 2]; d0.w = lvt[v][c0 + 3];
        d1.x = lvt[v][c0 + 4]; d1.y = lvt[v][c0 + 5];
        d1.z = lvt[v][c0 + 6]; d1.w = lvt[v][c0 + 7];
        float* dst = logitsVT + (size_t)(v0 + v) * TT + t0 + c0;
        *(float4*)dst       = d0;
        *(float4*)(dst + 4) = d1;
    }
}

// ---------------- kernel 2: merge softmax partials -> per-topic constant ----------------
// stats[t] = C_t = -log2(l_t) - m_t*log2e, so w[v][t] = exp2(logit*log2e + C_t)
__global__ __launch_bounds__(256) void merge_stats(const float* __restrict__ pm,
                                                   const float* __restrict__ pl,
                                                   float* __restrict__ stats) {
    const int tid = threadIdx.x;
    const int t = blockIdx.x;
    __shared__ float red[8];
    float m = -3.4e38f;
    for (int j = tid; j < NPART; j += 256) m = fmaxf(m, pm[t * NPART + j]);
#pragma unroll
    for (int off = 1; off < 64; off <<= 1) m = fmaxf(m, __shfl_xor(m, off));
    if ((tid & 63) == 0) red[tid >> 6] = m;
    __syncthreads();
    m = fmaxf(fmaxf(red[0], red[1]), fmaxf(red[2], red[3]));

    float l = 0.0f;
    for (int j = tid; j < NPART; j += 256)
        l += pl[t * NPART + j] * __expf(pm[t * NPART + j] - m);
#pragma unroll
    for (int off = 1; off < 64; off <<= 1) l += __shfl_xor(l, off);
    if ((tid & 63) == 0) red[4 + (tid >> 6)] = l;
    __syncthreads();
    if (tid == 0) {
        float tot = red[4] + red[5] + red[6] + red[7];
        stats[t] = -(__log2f(tot) + m * LOG2E);
    }
}

// ---------------- kernel 3: out[V,N] = softmax(logits) @ x  (fused; pipelined k-loop) ----------------
// R4 evidence: wx ~64 us vs ~25 us store-roofline. The unrolled k-loop couldn't
// hoist 32 B-loads (VGPR), so each kb exposed ~250 cyc of L2 latency. This
// version software-pipelines 1 kb ahead (double-buffered l/b registers, ~48 VGPR
// for 2 stages) and materializes A in-loop so exp2/cvt_pk overlap in-flight
// loads. __launch_bounds__(256,3) caps VGPR at 168 -> >=12 waves/CU.
__global__ __launch_bounds__(256, 3) void wx_mfma(const float* __restrict__ logitsVT,
                                                  const float* __restrict__ stats,
                                                  const unsigned short* __restrict__ xT,
                                                  float* __restrict__ out) {
    __shared__ float lvt[32][256];   // 32 KB staging, one v-half at a time
    const int g  = blockIdx.x;
    const int id = (g & 7) * 256 + (g >> 3);   // XCD-major linear id
    const int vt = id >> 2;                     // v-tile (64 rows)
    const int nc = id & 3;                      // n-chunk (256 cols)
    if (vt >= VV / 64) return;                  // 48 padded blocks idle-exit (block-uniform)

    const int tid = threadIdx.x;
    const int n0 = nc * 256;
    const int v0 = vt * 64;
    const int lane = tid & 63;
    const int wv   = tid >> 6;
    const int vh   = (wv & 1) * 32;             // wave's v-half
    const int nh   = (wv >> 1) * 128;           // wave's n-half
    const int r32  = lane & 31;
    const int koff = (lane >> 5) * 8;

    const float* __restrict__ lp = logitsVT + (size_t)(v0 + vh + r32) * TT + koff;
    const float* __restrict__ cp = stats + koff;
    const unsigned short* __restrict__ bp = xT + (size_t)(n0 + nh + r32) * TT + koff;

    // ---- software-pipelined k-loop: stage kb+1 loads under kb compute ----
    float4 l0[2], l1[2];
    short8 b[2][4];
    l0[0] = *(const float4*)(lp);
    l1[0] = *(const float4*)(lp + 4);
    b[0][0] = *(const short8*)(bp + (size_t)0 * 32 * TT);
    b[0][1] = *(const short8*)(bp + (size_t)1 * 32 * TT);
    b[0][2] = *(const short8*)(bp + (size_t)2 * 32 * TT);
    b[0][3] = *(const short8*)(bp + (size_t)3 * 32 * TT);

    float16 acc[4];
#pragma unroll
    for (int nt = 0; nt < 4; nt++) acc[nt] = (float16){0,0,0,0,0,0,0,0,0,0,0,0,0,0,0,0};

#pragma unroll
    for (int kb = 0; kb < 8; kb++) {
        const int cur = kb & 1;        // compile-time under full unroll
        const int nxt = cur ^ 1;
        if (kb < 7) {                  // issue next stage's loads first
            l0[nxt] = *(const float4*)(lp + (kb + 1) * 16);
            l1[nxt] = *(const float4*)(lp + (kb + 1) * 16 + 4);
            b[nxt][0] = *(const short8*)(bp + (size_t)0 * 32 * TT + (kb + 1) * 16);
            b[nxt][1] = *(const short8*)(bp + (size_t)1 * 32 * TT + (kb + 1) * 16);
            b[nxt][2] = *(const short8*)(bp + (size_t)2 * 32 * TT + (kb + 1) * 16);
            b[nxt][3] = *(const short8*)(bp + (size_t)3 * 32 * TT + (kb + 1) * 16);
        }
        float c[8];
#pragma unroll
        for (int j = 0; j < 8; j++) c[j] = cp[kb * 16 + j];  // L1-hit constants

        union { short8 v; unsigned u[4]; } a;
        a.u[0] = pack_bf16(exp2f(fmaf(l0[cur].x, LOG2E, c[0])), exp2f(fmaf(l0[cur].y, LOG2E, c[1])));
        a.u[1] = pack_bf16(exp2f(fmaf(l0[cur].z, LOG2E, c[2])), exp2f(fmaf(l0[cur].w, LOG2E, c[3])));
        a.u[2] = pack_bf16(exp2f(fmaf(l1[cur].x, LOG2E, c[4])), exp2f(fmaf(l1[cur].y, LOG2E, c[5])));
        a.u[3] = pack_bf16(exp2f(fmaf(l1[cur].z, LOG2E, c[6])), exp2f(fmaf(l1[cur].w, LOG2E, c[7])));

        acc[0] = __builtin_amdgcn_mfma_f32_32x32x16_bf16(a.v, b[cur][0], acc[0], 0, 0, 0);
        acc[1] = __builtin_amdgcn_mfma_f32_32x32x16_bf16(a.v, b[cur][1], acc[1], 0, 0, 0);
        acc[2] = __builtin_amdgcn_mfma_f32_32x32x16_bf16(a.v, b[cur][2], acc[2], 0, 0, 0);
        acc[3] = __builtin_amdgcn_mfma_f32_32x32x16_bf16(a.v, b[cur][3], acc[3], 0, 0, 0);
    }

    // ---- epilogue: LDS-staged, two v-halves, wide linear row stores ----
    const int col   = lane & 31;
    const int rbase = 4 * (lane >> 5);
#pragma unroll
    for (int half = 0; half < 2; half++) {
        if ((wv & 1) == half) {   // waves owning this v-half deposit their tiles
#pragma unroll
            for (int nt = 0; nt < 4; nt++) {
#pragma unroll
                for (int r = 0; r < 16; r++) {
                    int row = (r & 3) + 8 * (r >> 2) + rbase;  // measured C/D layout
                    lvt[row][nh + nt * 32 + col] = acc[nt][r];
                }
            }
        }
        __syncthreads();
        // all 4 waves store: wave wv owns rows wv, wv+4, ..., wv+28 (1 KB each)
#pragma unroll
        for (int j = 0; j < 8; j++) {
            int row = wv + j * 4;
            float4 d = *(const float4*)&lvt[row][lane * 4];
            *(float4*)(out + (size_t)(v0 + half * 32 + row) * NN + n0 + lane * 4) = d;
        }
        __syncthreads();  // lvt reused by next half
    }
}

extern "C" void kernel_launch(void* const* d_in, const int* in_sizes, int n_in,
                              void* d_out, int out_size, void* d_ws, size_t ws_size,
                              hipStream_t stream) {
    const float* x           = (const float*)d_in[0];  // [T,N]
    const float* mu          = (const float*)d_in[1];  // [V,E]
    const float* log_sigma   = (const float*)d_in[2];  // [V,E]
    const float* mu_c        = (const float*)d_in[3];  // [T,E]
    const float* log_sigma_c = (const float*)d_in[4];  // [T,E]
    float* out = (float*)d_out;

    // ws layout (floats): logitsVT [V*T] | pm [T*NPART] | pl [T*NPART] | stats [T]
    //                     | sc [T*E] | mc [T*E] | xT [N*T]/2
    float* ws       = (float*)d_ws;
    float* logitsVT = ws;
    float* pm       = logitsVT + (size_t)TT * VV;
    float* pl       = pm + (size_t)TT * NPART;
    float* stats    = pl + (size_t)TT * NPART;
    float* sc       = stats + TT;
    float* mc       = sc + TT * EE;
    unsigned short* xT = (unsigned short*)(mc + TT * EE);

    prep_xpose<<<64, 256, 0, stream>>>(mu_c, log_sigma_c, x, sc, mc, xT);
    logits_kernel<<<dim3(VV / 64, 4), 256, 0, stream>>>(mu, log_sigma, sc, mc,
                                                        logitsVT, pm, pl);
    merge_stats<<<TT, 256, 0, stream>>>(pm, pl, stats);
    wx_mfma<<<2048, 256, 0, stream>>>(logitsVT, stats, xT, out);
}

// Round 11
// 246.663 us; speedup vs baseline: 1.0042x; 1.0042x over previous
//
#include <hip/hip_runtime.h>
#include <math.h>

#define VV 32000
#define TT 128
#define EE 64
#define NN 1024
#define NPART 500   // one softmax partial per (topic, v-tile-block)

static constexpr float BOUND    = 1.41421356237309515f;   // sqrt(2)
static constexpr float LOG_SMIN = -2.30258509299404568f;  // log(0.1)
static constexpr float LOG_SMAX =  2.30258509299404568f;  // log(10)
static constexpr float LN2      =  0.69314718055994531f;
static constexpr float LOG2E    =  1.44269504088896340f;
static constexpr float E_LOG2PI =  64.0f * 1.83787706640934548f; // E*log(2*pi)

typedef __attribute__((ext_vector_type(2)))  float f32x2;    // -> v_pk_*_f32
typedef __attribute__((ext_vector_type(4)))  float f32x4;    // nt-store friendly
typedef __attribute__((ext_vector_type(8)))  short short8;   // 8 bf16 = 4 VGPRs
typedef __attribute__((ext_vector_type(16))) float float16;  // MFMA 32x32 acc

static __device__ inline unsigned short f2bf(float f) {
    union { float f; unsigned u; } v; v.f = f;
    unsigned r = v.u + 0x7FFFu + ((v.u >> 16) & 1u);  // round-to-nearest-even
    return (unsigned short)(r >> 16);
}

// one instruction packs two f32 -> two bf16 (RNE, identical to f2bf)
static __device__ inline unsigned pack_bf16(float a, float b) {
    unsigned r;
    asm("v_cvt_pk_bf16_f32 %0, %1, %2" : "=v"(r) : "v"(a), "v"(b));
    return r;
}

// ---------------- kernel 0: ctx clamp+exp (blocks 0..31) + x transpose (blocks 32..63) ----------------
__global__ __launch_bounds__(256) void prep_xpose(const float* __restrict__ mu_c,
                                                  const float* __restrict__ log_sigma_c,
                                                  const float* __restrict__ x,
                                                  float* __restrict__ sc,
                                                  float* __restrict__ mc,
                                                  unsigned short* __restrict__ xT) {
    const int tid = threadIdx.x;
    if (blockIdx.x < 32) {
        int i = blockIdx.x * 256 + tid;
        if (i < TT * EE) {
            float ls = log_sigma_c[i];
            ls = fminf(fmaxf(ls, LOG_SMIN), LOG_SMAX);
            sc[i] = __expf(ls);
            float m = mu_c[i];
            mc[i] = fminf(fmaxf(m, -BOUND), BOUND);
        }
    } else {
        // transpose x [T][N] -> xT [N][T] bf16. 32 blocks x 32 n-cols.
        const int b = blockIdx.x - 32;         // 0..31
        const int n = b * 32 + (tid & 31);
        const int th = tid >> 5;               // 0..7
        const float* __restrict__ xp = x + n;
#pragma unroll
        for (int i = 0; i < 16; i += 2) {
            int t = th * 16 + i;
            float x0 = xp[(size_t)t * NN];     // lanes -> consecutive n: coalesced
            float x1 = xp[(size_t)(t + 1) * NN];
            *(unsigned*)&xT[n * TT + t] = (unsigned)f2bf(x0) | ((unsigned)f2bf(x1) << 16);
        }
    }
}

// ---------------- kernel 1: logits [V][T] (row-major), E split across waves ----------------
__global__ __launch_bounds__(256) void logits_kernel(const float* __restrict__ mu,
                                                     const float* __restrict__ log_sigma,
                                                     const float* __restrict__ sc,
                                                     const float* __restrict__ mc,
                                                     float* __restrict__ logitsVT,
                                                     float* __restrict__ pm,
                                                     float* __restrict__ pl) {
    __shared__ float part[16][4][64];  // [t-in-phase][wave][lane] : 16 KB
    __shared__ float lvt[64][33];      // [v][t-in-block], +1 pad: col-write conflict-free
    const int tid  = threadIdx.x;
    const int lane = tid & 63;
    const int wv   = tid >> 6;
    const int v0   = blockIdx.x * 64;
    const int t0   = blockIdx.y * 32;
    const int e0u  = __builtin_amdgcn_readfirstlane(wv) * 16;  // provably uniform

    // per-lane slice of sigma_v / mu_v: v = v0+lane, e in [e0u, e0u+16)
    f32x2 sv[8], mv[8];
    {
        const float* __restrict__ lsp = log_sigma + (size_t)(v0 + lane) * EE + e0u;
        const float* __restrict__ mup = mu        + (size_t)(v0 + lane) * EE + e0u;
#pragma unroll
        for (int j = 0; j < 8; j++) {
            float a = lsp[2 * j], b = lsp[2 * j + 1];
            a = fminf(fmaxf(a, LOG_SMIN), LOG_SMAX);
            b = fminf(fmaxf(b, LOG_SMIN), LOG_SMAX);
            sv[j] = f32x2{__expf(a), __expf(b)};
            float c = mup[2 * j], d = mup[2 * j + 1];
            mv[j] = f32x2{fminf(fmaxf(c, -BOUND), BOUND), fminf(fmaxf(d, -BOUND), BOUND)};
        }
    }

    // double-buffered wave-uniform ctx slices (16 sc + 16 mc floats per topic)
    f32x2 cs[2][8], cm[2][8];
    {
        const f32x2* __restrict__ sp = (const f32x2*)(sc + t0 * EE + e0u);
        const f32x2* __restrict__ mp = (const f32x2*)(mc + t0 * EE + e0u);
#pragma unroll
        for (int j = 0; j < 8; j++) { cs[0][j] = sp[j]; cm[0][j] = mp[j]; }
    }

    for (int tb = 0; tb < 2; tb++) {           // 2 phases x 16 topics = 32 topics
#pragma unroll
        for (int i = 0; i < 16; i++) {
            const int ti  = tb * 16 + i;       // 0..31 within block
            const int cur = ti & 1;
            if (ti < 31) {                     // prefetch next topic's slice
                const int tn = t0 + ti + 1;
                const f32x2* __restrict__ sp = (const f32x2*)(sc + tn * EE + e0u);
                const f32x2* __restrict__ mp = (const f32x2*)(mc + tn * EE + e0u);
#pragma unroll
                for (int j = 0; j < 8; j++) { cs[cur ^ 1][j] = sp[j]; cm[cur ^ 1][j] = mp[j]; }
            }
            f32x2 q = {0.f, 0.f};
            f32x2 p = {1.f, 1.f};
#pragma unroll
            for (int j = 0; j < 8; j++) {
                f32x2 s = sv[j] + cs[cur][j];   // v_pk_add_f32
                p *= s;                          // v_pk_mul_f32
                f32x2 d = mv[j] - cm[cur][j];
                f32x2 r;
                r.x = __builtin_amdgcn_rcpf(s.x);
                r.y = __builtin_amdgcn_rcpf(s.y);
                q += d * d * r;
            }
            // 16 factors, s in [0.2,20]: product in [6.6e-12, 6.6e20] — fp32 safe
            part[i][wv][lane] = __log2f(p.x * p.y) * LN2 + q.x + q.y;
        }
        __syncthreads();
        // finalize: wave wv owns topics i = 4*wv..4*wv+3 of this phase
#pragma unroll
        for (int k = 0; k < 4; k++) {
            const int i = wv * 4 + k;
            const int t = t0 + tb * 16 + i;
            float sum = part[i][0][lane] + part[i][1][lane] + part[i][2][lane] + part[i][3][lane];
            float logit = -0.5f * (sum + E_LOG2PI);
            lvt[lane][tb * 16 + i] = logit;    // stride-33 column write: conflict-free

            float m = logit;
#pragma unroll
            for (int off = 1; off < 64; off <<= 1) m = fmaxf(m, __shfl_xor(m, off));
            float sx = __expf(logit - m);
#pragma unroll
            for (int off = 1; off < 64; off <<= 1) sx += __shfl_xor(sx, off);
            if (lane == 0) {
                pm[t * NPART + blockIdx.x] = m;
                pl[t * NPART + blockIdx.x] = sx;
            }
        }
        __syncthreads();  // part[] reused next phase; also covers lvt before writeout
    }

    // write-out: [V][T] rows, 8 floats (32 B) per thread, 128 B per 4-thread group
    {
        const int v  = tid >> 2;
        const int c0 = (tid & 3) * 8;
        float4 d0, d1;
        d0.x = lvt[v][c0 + 0]; d0.y = lvt[v][c0 + 1];
        d0.z = lvt[v][c0 + 2]; d0.w = lvt[v][c0 + 3];
        d1.x = lvt[v][c0 + 4]; d1.y = lvt[v][c0 + 5];
        d1.z = lvt[v][c0 + 6]; d1.w = lvt[v][c0 + 7];
        float* dst = logitsVT + (size_t)(v0 + v) * TT + t0 + c0;
        *(float4*)dst       = d0;
        *(float4*)(dst + 4) = d1;
    }
}

// ---------------- kernel 2: merge softmax partials -> per-topic constant ----------------
// stats[t] = C_t = -log2(l_t) - m_t*log2e, so w[v][t] = exp2(logit*log2e + C_t)
__global__ __launch_bounds__(256) void merge_stats(const float* __restrict__ pm,
                                                   const float* __restrict__ pl,
                                                   float* __restrict__ stats) {
    const int tid = threadIdx.x;
    const int t = blockIdx.x;
    __shared__ float red[8];
    float m = -3.4e38f;
    for (int j = tid; j < NPART; j += 256) m = fmaxf(m, pm[t * NPART + j]);
#pragma unroll
    for (int off = 1; off < 64; off <<= 1) m = fmaxf(m, __shfl_xor(m, off));
    if ((tid & 63) == 0) red[tid >> 6] = m;
    __syncthreads();
    m = fmaxf(fmaxf(red[0], red[1]), fmaxf(red[2], red[3]));

    float l = 0.0f;
    for (int j = tid; j < NPART; j += 256)
        l += pl[t * NPART + j] * __expf(pm[t * NPART + j] - m);
#pragma unroll
    for (int off = 1; off < 64; off <<= 1) l += __shfl_xor(l, off);
    if ((tid & 63) == 0) red[4 + (tid >> 6)] = l;
    __syncthreads();
    if (tid == 0) {
        float tot = red[4] + red[5] + red[6] + red[7];
        stats[t] = -(__log2f(tot) + m * LOG2E);
    }
}

// ---------------- kernel 3: out[V,N] = softmax(logits) @ x  (r4 structure + NT stores) ----------------
// EXACT round-4 kernel (measured best, 238.2 total) with ONE change: the out
// stores are non-temporal (global_store_dwordx4 nt), bypassing L2 allocation.
// Rationale: wx_r4 ~64 us vs ~23 us store floor; stores are already 1 KB
// contiguous per wave-instruction, yet effective write BW is ~2.0 TB/s vs
// fillBuffer's 6.5. Remaining structural difference: each XCD streams a
// write-only 16.4 MB slab through its 4 MB L2 (allocate + dirty-evict).
// NT stores make the write stream first-class to HBM.
// (r6's manual pipeline + launch_bounds(256,3) regressed +9.5 us — reverted.)
__global__ __launch_bounds__(256) void wx_mfma(const float* __restrict__ logitsVT,
                                               const float* __restrict__ stats,
                                               const unsigned short* __restrict__ xT,
                                               float* __restrict__ out) {
    __shared__ float lvt[32][256];   // 32 KB staging, one v-half at a time
    const int g  = blockIdx.x;
    const int id = (g & 7) * 256 + (g >> 3);   // XCD-major linear id
    const int vt = id >> 2;                     // v-tile (64 rows)
    const int nc = id & 3;                      // n-chunk (256 cols)
    if (vt >= VV / 64) return;                  // 48 padded blocks idle-exit

    const int tid = threadIdx.x;
    const int n0 = nc * 256;
    const int v0 = vt * 64;
    const int lane = tid & 63;
    const int wv   = tid >> 6;
    const int vh   = (wv & 1) * 32;             // wave's v-half
    const int nh   = (wv >> 1) * 128;           // wave's n-half
    const int r32  = lane & 31;
    const int koff = (lane >> 5) * 8;

    // ---- A: softmax weights for 32 v-rows x 128 topics, computed once ----
    short8 a[8];
    {
        const float* __restrict__ lp = logitsVT + (size_t)(v0 + vh + r32) * TT + koff;
        const float* __restrict__ cp = stats + koff;
#pragma unroll
        for (int kb = 0; kb < 8; kb++) {
            float4 l0 = *(const float4*)(lp + kb * 16);
            float4 l1 = *(const float4*)(lp + kb * 16 + 4);
            float c[8];
#pragma unroll
            for (int j = 0; j < 8; j++) c[j] = cp[kb * 16 + j];
            union { short8 v; unsigned u[4]; } t;
            t.u[0] = pack_bf16(exp2f(fmaf(l0.x, LOG2E, c[0])), exp2f(fmaf(l0.y, LOG2E, c[1])));
            t.u[1] = pack_bf16(exp2f(fmaf(l0.z, LOG2E, c[2])), exp2f(fmaf(l0.w, LOG2E, c[3])));
            t.u[2] = pack_bf16(exp2f(fmaf(l1.x, LOG2E, c[4])), exp2f(fmaf(l1.y, LOG2E, c[5])));
            t.u[3] = pack_bf16(exp2f(fmaf(l1.z, LOG2E, c[6])), exp2f(fmaf(l1.w, LOG2E, c[7])));
            a[kb] = t.v;
        }
    }

    // ---- MFMA: 4 n-subtiles x 8 kb; kb outer -> 4 indep MFMAs + 4 batched loads ----
    const unsigned short* __restrict__ bp = xT + (size_t)(n0 + nh + r32) * TT + koff;
    float16 acc[4];
#pragma unroll
    for (int nt = 0; nt < 4; nt++) acc[nt] = (float16){0,0,0,0,0,0,0,0,0,0,0,0,0,0,0,0};
#pragma unroll
    for (int kb = 0; kb < 8; kb++) {
        short8 b0 = *(const short8*)(bp + (size_t)0 * 32 * TT + kb * 16);
        short8 b1 = *(const short8*)(bp + (size_t)1 * 32 * TT + kb * 16);
        short8 b2 = *(const short8*)(bp + (size_t)2 * 32 * TT + kb * 16);
        short8 b3 = *(const short8*)(bp + (size_t)3 * 32 * TT + kb * 16);
        acc[0] = __builtin_amdgcn_mfma_f32_32x32x16_bf16(a[kb], b0, acc[0], 0, 0, 0);
        acc[1] = __builtin_amdgcn_mfma_f32_32x32x16_bf16(a[kb], b1, acc[1], 0, 0, 0);
        acc[2] = __builtin_amdgcn_mfma_f32_32x32x16_bf16(a[kb], b2, acc[2], 0, 0, 0);
        acc[3] = __builtin_amdgcn_mfma_f32_32x32x16_bf16(a[kb], b3, acc[3], 0, 0, 0);
    }

    // ---- epilogue: LDS-staged, two v-halves, wide linear NT row stores ----
    const int col   = lane & 31;
    const int rbase = 4 * (lane >> 5);
#pragma unroll
    for (int half = 0; half < 2; half++) {
        if ((wv & 1) == half) {   // waves owning this v-half deposit their tiles
#pragma unroll
            for (int nt = 0; nt < 4; nt++) {
#pragma unroll
                for (int r = 0; r < 16; r++) {
                    int row = (r & 3) + 8 * (r >> 2) + rbase;  // measured C/D layout
                    lvt[row][nh + nt * 32 + col] = acc[nt][r];
                }
            }
        }
        __syncthreads();
        // all 4 waves store: wave wv owns rows wv, wv+4, ..., wv+28 (1 KB each)
#pragma unroll
        for (int j = 0; j < 8; j++) {
            int row = wv + j * 4;
            f32x4 d = *(const f32x4*)&lvt[row][lane * 4];
            __builtin_nontemporal_store(
                d, (f32x4*)(out + (size_t)(v0 + half * 32 + row) * NN + n0 + lane * 4));
        }
        __syncthreads();  // lvt reused by next half
    }
}

extern "C" void kernel_launch(void* const* d_in, const int* in_sizes, int n_in,
                              void* d_out, int out_size, void* d_ws, size_t ws_size,
                              hipStream_t stream) {
    const float* x           = (const float*)d_in[0];  // [T,N]
    const float* mu          = (const float*)d_in[1];  // [V,E]
    const float* log_sigma   = (const float*)d_in[2];  // [V,E]
    const float* mu_c        = (const float*)d_in[3];  // [T,E]
    const float* log_sigma_c = (const float*)d_in[4];  // [T,E]
    float* out = (float*)d_out;

    // ws layout (floats): logitsVT [V*T] | pm [T*NPART] | pl [T*NPART] | stats [T]
    //                     | sc [T*E] | mc [T*E] | xT [N*T]/2
    float* ws       = (float*)d_ws;
    float* logitsVT = ws;
    float* pm       = logitsVT + (size_t)TT * VV;
    float* pl       = pm + (size_t)TT * NPART;
    float* stats    = pl + (size_t)TT * NPART;
    float* sc       = stats + TT;
    float* mc       = sc + TT * EE;
    unsigned short* xT = (unsigned short*)(mc + TT * EE);

    prep_xpose<<<64, 256, 0, stream>>>(mu_c, log_sigma_c, x, sc, mc, xT);
    logits_kernel<<<dim3(VV / 64, 4), 256, 0, stream>>>(mu, log_sigma, sc, mc,
                                                        logitsVT, pm, pl);
    merge_stats<<<TT, 256, 0, stream>>>(pm, pl, stats);
    wx_mfma<<<2048, 256, 0, stream>>>(logitsVT, stats, xT, out);
}

// Round 15
// 237.910 us; speedup vs baseline: 1.0412x; 1.0368x over previous
//
#include <hip/hip_runtime.h>
#include <math.h>

#define VV 32000
#define TT 128
#define EE 64
#define NN 1024
#define NPART 500   // one softmax partial per (topic, v-tile-block)

static constexpr float BOUND    = 1.41421356237309515f;   // sqrt(2)
static constexpr float LOG_SMIN = -2.30258509299404568f;  // log(0.1)
static constexpr float LOG_SMAX =  2.30258509299404568f;  // log(10)
static constexpr float LN2      =  0.69314718055994531f;
static constexpr float LOG2E    =  1.44269504088896340f;
static constexpr float E_LOG2PI =  64.0f * 1.83787706640934548f; // E*log(2*pi)

typedef __attribute__((ext_vector_type(2)))  float f32x2;    // -> v_pk_*_f32
typedef __attribute__((ext_vector_type(8)))  short short8;   // 8 bf16 = 4 VGPRs
typedef __attribute__((ext_vector_type(16))) float float16;  // MFMA 32x32 acc

static __device__ inline unsigned short f2bf(float f) {
    union { float f; unsigned u; } v; v.f = f;
    unsigned r = v.u + 0x7FFFu + ((v.u >> 16) & 1u);  // round-to-nearest-even
    return (unsigned short)(r >> 16);
}

// one instruction packs two f32 -> two bf16 (RNE, identical to f2bf)
static __device__ inline unsigned pack_bf16(float a, float b) {
    unsigned r;
    asm("v_cvt_pk_bf16_f32 %0, %1, %2" : "=v"(r) : "v"(a), "v"(b));
    return r;
}

// LDS-only barrier: waits LDS ops (lgkmcnt) but lets global STORES stay in
// flight. __syncthreads() would emit s_waitcnt vmcnt(0) before s_barrier,
// putting ~600-900cy of HBM store completion on the critical path (twice per
// block in the wx epilogue). Correctness here needs only LDS visibility.
// (HW-verified pattern: learn_hip m218 — vmem ops survive raw s_barrier.)
static __device__ inline void lds_barrier() {
    asm volatile("s_waitcnt lgkmcnt(0)" ::: "memory");
    __builtin_amdgcn_s_barrier();
}

// ---------------- kernel 0: ctx clamp+exp (blocks 0..31) + x transpose (blocks 32..63) ----------------
__global__ __launch_bounds__(256) void prep_xpose(const float* __restrict__ mu_c,
                                                  const float* __restrict__ log_sigma_c,
                                                  const float* __restrict__ x,
                                                  float* __restrict__ sc,
                                                  float* __restrict__ mc,
                                                  unsigned short* __restrict__ xT) {
    const int tid = threadIdx.x;
    if (blockIdx.x < 32) {
        int i = blockIdx.x * 256 + tid;
        if (i < TT * EE) {
            float ls = log_sigma_c[i];
            ls = fminf(fmaxf(ls, LOG_SMIN), LOG_SMAX);
            sc[i] = __expf(ls);
            float m = mu_c[i];
            mc[i] = fminf(fmaxf(m, -BOUND), BOUND);
        }
    } else {
        // transpose x [T][N] -> xT [N][T] bf16. 32 blocks x 32 n-cols.
        const int b = blockIdx.x - 32;         // 0..31
        const int n = b * 32 + (tid & 31);
        const int th = tid >> 5;               // 0..7
        const float* __restrict__ xp = x + n;
#pragma unroll
        for (int i = 0; i < 16; i += 2) {
            int t = th * 16 + i;
            float x0 = xp[(size_t)t * NN];     // lanes -> consecutive n: coalesced
            float x1 = xp[(size_t)(t + 1) * NN];
            *(unsigned*)&xT[n * TT + t] = (unsigned)f2bf(x0) | ((unsigned)f2bf(x1) << 16);
        }
    }
}

// ---------------- kernel 1: logits [V][T] (row-major), E split across waves ----------------
__global__ __launch_bounds__(256) void logits_kernel(const float* __restrict__ mu,
                                                     const float* __restrict__ log_sigma,
                                                     const float* __restrict__ sc,
                                                     const float* __restrict__ mc,
                                                     float* __restrict__ logitsVT,
                                                     float* __restrict__ pm,
                                                     float* __restrict__ pl) {
    __shared__ float part[16][4][64];  // [t-in-phase][wave][lane] : 16 KB
    __shared__ float lvt[64][33];      // [v][t-in-block], +1 pad: col-write conflict-free
    const int tid  = threadIdx.x;
    const int lane = tid & 63;
    const int wv   = tid >> 6;
    const int v0   = blockIdx.x * 64;
    const int t0   = blockIdx.y * 32;
    const int e0u  = __builtin_amdgcn_readfirstlane(wv) * 16;  // provably uniform

    // per-lane slice of sigma_v / mu_v: v = v0+lane, e in [e0u, e0u+16)
    f32x2 sv[8], mv[8];
    {
        const float* __restrict__ lsp = log_sigma + (size_t)(v0 + lane) * EE + e0u;
        const float* __restrict__ mup = mu        + (size_t)(v0 + lane) * EE + e0u;
#pragma unroll
        for (int j = 0; j < 8; j++) {
            float a = lsp[2 * j], b = lsp[2 * j + 1];
            a = fminf(fmaxf(a, LOG_SMIN), LOG_SMAX);
            b = fminf(fmaxf(b, LOG_SMIN), LOG_SMAX);
            sv[j] = f32x2{__expf(a), __expf(b)};
            float c = mup[2 * j], d = mup[2 * j + 1];
            mv[j] = f32x2{fminf(fmaxf(c, -BOUND), BOUND), fminf(fmaxf(d, -BOUND), BOUND)};
        }
    }

    // double-buffered wave-uniform ctx slices (16 sc + 16 mc floats per topic)
    f32x2 cs[2][8], cm[2][8];
    {
        const f32x2* __restrict__ sp = (const f32x2*)(sc + t0 * EE + e0u);
        const f32x2* __restrict__ mp = (const f32x2*)(mc + t0 * EE + e0u);
#pragma unroll
        for (int j = 0; j < 8; j++) { cs[0][j] = sp[j]; cm[0][j] = mp[j]; }
    }

    for (int tb = 0; tb < 2; tb++) {           // 2 phases x 16 topics = 32 topics
#pragma unroll
        for (int i = 0; i < 16; i++) {
            const int ti  = tb * 16 + i;       // 0..31 within block
            const int cur = ti & 1;
            if (ti < 31) {                     // prefetch next topic's slice
                const int tn = t0 + ti + 1;
                const f32x2* __restrict__ sp = (const f32x2*)(sc + tn * EE + e0u);
                const f32x2* __restrict__ mp = (const f32x2*)(mc + tn * EE + e0u);
#pragma unroll
                for (int j = 0; j < 8; j++) { cs[cur ^ 1][j] = sp[j]; cm[cur ^ 1][j] = mp[j]; }
            }
            f32x2 q = {0.f, 0.f};
            f32x2 p = {1.f, 1.f};
#pragma unroll
            for (int j = 0; j < 8; j++) {
                f32x2 s = sv[j] + cs[cur][j];   // v_pk_add_f32
                p *= s;                          // v_pk_mul_f32
                f32x2 d = mv[j] - cm[cur][j];
                f32x2 r;
                r.x = __builtin_amdgcn_rcpf(s.x);
                r.y = __builtin_amdgcn_rcpf(s.y);
                q += d * d * r;
            }
            // 16 factors, s in [0.2,20]: product in [6.6e-12, 6.6e20] — fp32 safe
            part[i][wv][lane] = __log2f(p.x * p.y) * LN2 + q.x + q.y;
        }
        __syncthreads();
        // finalize: wave wv owns topics i = 4*wv..4*wv+3 of this phase
#pragma unroll
        for (int k = 0; k < 4; k++) {
            const int i = wv * 4 + k;
            const int t = t0 + tb * 16 + i;
            float sum = part[i][0][lane] + part[i][1][lane] + part[i][2][lane] + part[i][3][lane];
            float logit = -0.5f * (sum + E_LOG2PI);
            lvt[lane][tb * 16 + i] = logit;    // stride-33 column write: conflict-free

            float m = logit;
#pragma unroll
            for (int off = 1; off < 64; off <<= 1) m = fmaxf(m, __shfl_xor(m, off));
            float sx = __expf(logit - m);
#pragma unroll
            for (int off = 1; off < 64; off <<= 1) sx += __shfl_xor(sx, off);
            if (lane == 0) {
                pm[t * NPART + blockIdx.x] = m;
                pl[t * NPART + blockIdx.x] = sx;
            }
        }
        __syncthreads();  // part[] reused next phase; also covers lvt before writeout
    }

    // write-out: [V][T] rows, 8 floats (32 B) per thread, 128 B per 4-thread group
    {
        const int v  = tid >> 2;
        const int c0 = (tid & 3) * 8;
        float4 d0, d1;
        d0.x = lvt[v][c0 + 0]; d0.y = lvt[v][c0 + 1];
        d0.z = lvt[v][c0 + 2]; d0.w = lvt[v][c0 + 3];
        d1.x = lvt[v][c0 + 4]; d1.y = lvt[v][c0 + 5];
        d1.z = lvt[v][c0 + 6]; d1.w = lvt[v][c0 + 7];
        float* dst = logitsVT + (size_t)(v0 + v) * TT + t0 + c0;
        *(float4*)dst       = d0;
        *(float4*)(dst + 4) = d1;
    }
}

// ---------------- kernel 2: merge softmax partials -> per-topic constant ----------------
// stats[t] = C_t = -log2(l_t) - m_t*log2e, so w[v][t] = exp2(logit*log2e + C_t)
__global__ __launch_bounds__(256) void merge_stats(const float* __restrict__ pm,
                                                   const float* __restrict__ pl,
                                                   float* __restrict__ stats) {
    const int tid = threadIdx.x;
    const int t = blockIdx.x;
    __shared__ float red[8];
    float m = -3.4e38f;
    for (int j = tid; j < NPART; j += 256) m = fmaxf(m, pm[t * NPART + j]);
#pragma unroll
    for (int off = 1; off < 64; off <<= 1) m = fmaxf(m, __shfl_xor(m, off));
    if ((tid & 63) == 0) red[tid >> 6] = m;
    __syncthreads();
    m = fmaxf(fmaxf(red[0], red[1]), fmaxf(red[2], red[3]));

    float l = 0.0f;
    for (int j = tid; j < NPART; j += 256)
        l += pl[t * NPART + j] * __expf(pm[t * NPART + j] - m);
#pragma unroll
    for (int off = 1; off < 64; off <<= 1) l += __shfl_xor(l, off);
    if ((tid & 63) == 0) red[4 + (tid >> 6)] = l;
    __syncthreads();
    if (tid == 0) {
        float tot = red[4] + red[5] + red[6] + red[7];
        stats[t] = -(__log2f(tot) + m * LOG2E);
    }
}

// ---------------- kernel 3: out[V,N] = softmax(logits) @ x  (r4 structure + LDS-only barriers) ----------------
// EXACT round-4 kernel (measured best, 238.2 total; NT-store variant r11 was
// +8.5 us -> reverted to plain stores) with ONE change: the two epilogue
// __syncthreads() become lds_barrier() (s_waitcnt lgkmcnt(0) + raw s_barrier).
// __syncthreads drains vmcnt(0) -> every wave stalled ~600-900cy on HBM store
// COMPLETION twice per block, serializing the write stream (~2 TB/s observed
// vs 6.5 fillBuffer). The barrier here only needs LDS visibility; stores from
// half 0 now complete under half 1's work and across blocks.
__global__ __launch_bounds__(256) void wx_mfma(const float* __restrict__ logitsVT,
                                               const float* __restrict__ stats,
                                               const unsigned short* __restrict__ xT,
                                               float* __restrict__ out) {
    __shared__ float lvt[32][256];   // 32 KB staging, one v-half at a time
    const int g  = blockIdx.x;
    const int id = (g & 7) * 256 + (g >> 3);   // XCD-major linear id
    const int vt = id >> 2;                     // v-tile (64 rows)
    const int nc = id & 3;                      // n-chunk (256 cols)
    if (vt >= VV / 64) return;                  // 48 padded blocks idle-exit

    const int tid = threadIdx.x;
    const int n0 = nc * 256;
    const int v0 = vt * 64;
    const int lane = tid & 63;
    const int wv   = tid >> 6;
    const int vh   = (wv & 1) * 32;             // wave's v-half
    const int nh   = (wv >> 1) * 128;           // wave's n-half
    const int r32  = lane & 31;
    const int koff = (lane >> 5) * 8;

    // ---- A: softmax weights for 32 v-rows x 128 topics, computed once ----
    short8 a[8];
    {
        const float* __restrict__ lp = logitsVT + (size_t)(v0 + vh + r32) * TT + koff;
        const float* __restrict__ cp = stats + koff;
#pragma unroll
        for (int kb = 0; kb < 8; kb++) {
            float4 l0 = *(const float4*)(lp + kb * 16);
            float4 l1 = *(const float4*)(lp + kb * 16 + 4);
            float c[8];
#pragma unroll
            for (int j = 0; j < 8; j++) c[j] = cp[kb * 16 + j];
            union { short8 v; unsigned u[4]; } t;
            t.u[0] = pack_bf16(exp2f(fmaf(l0.x, LOG2E, c[0])), exp2f(fmaf(l0.y, LOG2E, c[1])));
            t.u[1] = pack_bf16(exp2f(fmaf(l0.z, LOG2E, c[2])), exp2f(fmaf(l0.w, LOG2E, c[3])));
            t.u[2] = pack_bf16(exp2f(fmaf(l1.x, LOG2E, c[4])), exp2f(fmaf(l1.y, LOG2E, c[5])));
            t.u[3] = pack_bf16(exp2f(fmaf(l1.z, LOG2E, c[6])), exp2f(fmaf(l1.w, LOG2E, c[7])));
            a[kb] = t.v;
        }
    }

    // ---- MFMA: 4 n-subtiles x 8 kb; kb outer -> 4 indep MFMAs + 4 batched loads ----
    const unsigned short* __restrict__ bp = xT + (size_t)(n0 + nh + r32) * TT + koff;
    float16 acc[4];
#pragma unroll
    for (int nt = 0; nt < 4; nt++) acc[nt] = (float16){0,0,0,0,0,0,0,0,0,0,0,0,0,0,0,0};
#pragma unroll
    for (int kb = 0; kb < 8; kb++) {
        short8 b0 = *(const short8*)(bp + (size_t)0 * 32 * TT + kb * 16);
        short8 b1 = *(const short8*)(bp + (size_t)1 * 32 * TT + kb * 16);
        short8 b2 = *(const short8*)(bp + (size_t)2 * 32 * TT + kb * 16);
        short8 b3 = *(const short8*)(bp + (size_t)3 * 32 * TT + kb * 16);
        acc[0] = __builtin_amdgcn_mfma_f32_32x32x16_bf16(a[kb], b0, acc[0], 0, 0, 0);
        acc[1] = __builtin_amdgcn_mfma_f32_32x32x16_bf16(a[kb], b1, acc[1], 0, 0, 0);
        acc[2] = __builtin_amdgcn_mfma_f32_32x32x16_bf16(a[kb], b2, acc[2], 0, 0, 0);
        acc[3] = __builtin_amdgcn_mfma_f32_32x32x16_bf16(a[kb], b3, acc[3], 0, 0, 0);
    }

    // ---- epilogue: LDS-staged, two v-halves, wide linear row stores ----
    const int col   = lane & 31;
    const int rbase = 4 * (lane >> 5);
#pragma unroll
    for (int half = 0; half < 2; half++) {
        if ((wv & 1) == half) {   // waves owning this v-half deposit their tiles
#pragma unroll
            for (int nt = 0; nt < 4; nt++) {
#pragma unroll
                for (int r = 0; r < 16; r++) {
                    int row = (r & 3) + 8 * (r >> 2) + rbase;  // measured C/D layout
                    lvt[row][nh + nt * 32 + col] = acc[nt][r];
                }
            }
        }
        lds_barrier();   // LDS visible; prior global stores stay in flight
        // all 4 waves store: wave wv owns rows wv, wv+4, ..., wv+28 (1 KB each)
#pragma unroll
        for (int j = 0; j < 8; j++) {
            int row = wv + j * 4;
            float4 d = *(const float4*)&lvt[row][lane * 4];
            *(float4*)(out + (size_t)(v0 + half * 32 + row) * NN + n0 + lane * 4) = d;
        }
        lds_barrier();   // lvt reuse ordering only — no vmcnt drain
    }
}

extern "C" void kernel_launch(void* const* d_in, const int* in_sizes, int n_in,
                              void* d_out, int out_size, void* d_ws, size_t ws_size,
                              hipStream_t stream) {
    const float* x           = (const float*)d_in[0];  // [T,N]
    const float* mu          = (const float*)d_in[1];  // [V,E]
    const float* log_sigma   = (const float*)d_in[2];  // [V,E]
    const float* mu_c        = (const float*)d_in[3];  // [T,E]
    const float* log_sigma_c = (const float*)d_in[4];  // [T,E]
    float* out = (float*)d_out;

    // ws layout (floats): logitsVT [V*T] | pm [T*NPART] | pl [T*NPART] | stats [T]
    //                     | sc [T*E] | mc [T*E] | xT [N*T]/2
    float* ws       = (float*)d_ws;
    float* logitsVT = ws;
    float* pm       = logitsVT + (size_t)TT * VV;
    float* pl       = pm + (size_t)TT * NPART;
    float* stats    = pl + (size_t)TT * NPART;
    float* sc       = stats + TT;
    float* mc       = sc + TT * EE;
    unsigned short* xT = (unsigned short*)(mc + TT * EE);

    prep_xpose<<<64, 256, 0, stream>>>(mu_c, log_sigma_c, x, sc, mc, xT);
    logits_kernel<<<dim3(VV / 64, 4), 256, 0, stream>>>(mu, log_sigma, sc, mc,
                                                        logitsVT, pm, pl);
    merge_stats<<<TT, 256, 0, stream>>>(pm, pl, stats);
    wx_mfma<<<2048, 256, 0, stream>>>(logitsVT, stats, xT, out);
}